// Round 9
// baseline (65.654 us; speedup 1.0000x reference)
//
#include <hip/hip_runtime.h>
#include <hip/hip_bf16.h>

// LengthRegulator, phoneme-centric: x [B=32,T=512,D=512] f32,
// duration [B,T] int32, max_len=4096. out0: [B,ML,D] f32, out1: mel_len [B] f32.
//
// R8 lesson: store layout was NOT the limiter (63.7us ~= 64.1us). Arithmetic
// says the limiter is prologue overhead: 2304 blocks x ~1.5us redundant scan
// ~= 35% of the 10,000 CU-us budget at the 39us store roofline.
// R9 change: kPhonPerBlock 8 -> 64 (each wave owns 8 phonemes, strided),
// grid 2304 -> 512 blocks, prologue amortized 8x. Row loads for all 8
// phonemes issued up front (unrolled) so store loops pipeline against loads.

typedef float f32x4 __attribute__((ext_vector_type(4)));

constexpr int B   = 32;
constexpr int T   = 512;
constexpr int D   = 512;
constexpr int D4  = D / 4;        // 128 x 16B per row
constexpr int ML  = 4096;
constexpr int NTHREADS = 512;
constexpr int kPhonPerBlock = 64;                    // 8 per wave
constexpr int kPhonPerWave  = kPhonPerBlock / 8;     // 8
constexpr int kNumExp  = T / kPhonPerBlock;          // 8 expand blocks / batch
constexpr int kZChunk  = 512;                        // frames per zerofill block
constexpr int kNumZero = ML / kZChunk;               // 8 zerofill blocks / batch
constexpr int kBlocksPerBatch = kNumExp + kNumZero;  // 16 blocks per batch

__global__ __launch_bounds__(NTHREADS) void lr_expand(
    const int*   __restrict__ duration,  // [B, T]
    const f32x4* __restrict__ x,         // [B, T, D4]
    f32x4*       __restrict__ out,       // [B, ML, D4]
    float*       __restrict__ mel_out)   // [B]
{
    const int b    = blockIdx.x / kBlocksPerBatch;
    const int r    = blockIdx.x % kBlocksPerBatch;
    const int t    = threadIdx.x;
    const int lane = t & 63;
    const int wave = t >> 6;             // 8 waves

    __shared__ int csum[T];
    __shared__ int wsum[NTHREADS / 64];

    // ---- batch scan prologue: inclusive csum of duration[b,:] ----
    int v = duration[b * T + t];
    #pragma unroll
    for (int off = 1; off < 64; off <<= 1) {
        int n = __shfl_up(v, off, 64);
        if (lane >= off) v += n;
    }
    if (lane == 63) wsum[wave] = v;
    __syncthreads();
    int prev = 0;
    #pragma unroll
    for (int w = 0; w < NTHREADS / 64; ++w)
        if (w < wave) prev += wsum[w];
    v += prev;
    csum[t] = v;
    __syncthreads();

    const int mel = csum[T - 1];

    if (r < kNumExp) {
        // ---- expand: this wave owns 8 strided phonemes ----
        const int pbase = r * kPhonPerBlock + wave;   // p = pbase + 8k

        if (r == 0 && t == 0)
            mel_out[b] = (float)mel;

        // issue all row loads up front (pipelines against store loops)
        f32x4 v0[kPhonPerWave], v1[kPhonPerWave];
        #pragma unroll
        for (int k = 0; k < kPhonPerWave; ++k) {
            const int p = pbase + 8 * k;
            const size_t xbase = ((size_t)(b * T + p)) * D4;
            v0[k] = x[xbase + lane];        // first 1KB of row
            v1[k] = x[xbase + 64 + lane];   // second 1KB of row
        }

        #pragma unroll
        for (int k = 0; k < kPhonPerWave; ++k) {
            const int p     = pbase + 8 * k;
            const int end   = csum[p];
            const int start = (p == 0) ? 0 : csum[p - 1];
            size_t o = ((size_t)(b * ML + start)) * D4;
            for (int j = start; j < end; ++j, o += D4) {
                out[o + lane]      = v0[k];   // 1KB contiguous per instr
                out[o + 64 + lane] = v1[k];
            }
        }
    } else {
        // ---- zerofill: frames [max(j0, mel), j0+kZChunk) ----
        const int c  = r - kNumExp;
        const int j0 = c * kZChunk;
        int fstart = mel - j0;
        if (fstart >= kZChunk) return;       // chunk fully valid
        if (fstart < 0) fstart = 0;
        const int total = (kZChunk - fstart) * D4;
        const size_t base = ((size_t)(b * ML + j0 + fstart)) * D4;
        const f32x4 zero = {0.f, 0.f, 0.f, 0.f};
        for (int m = t; m < total; m += NTHREADS)
            out[base + m] = zero;
    }
}

extern "C" void kernel_launch(void* const* d_in, const int* in_sizes, int n_in,
                              void* d_out, int out_size, void* d_ws, size_t ws_size,
                              hipStream_t stream) {
    const float* x   = (const float*)d_in[0];
    const int*   dur = (const int*)d_in[1];

    float* out     = (float*)d_out;                 // [B*ML*D] then [B]
    float* mel_out = out + (size_t)B * ML * D;

    lr_expand<<<B * kBlocksPerBatch, NTHREADS, 0, stream>>>(
        dur, (const f32x4*)x, (f32x4*)out, mel_out);
}

// Round 10
// 58.082 us; speedup vs baseline: 1.1304x; 1.1304x over previous
//
#include <hip/hip_runtime.h>
#include <hip/hip_bf16.h>

// LengthRegulator: x [B=32,T=512,D=512] f32, duration [B,T] int32, max_len=4096.
// out0: [B,ML,D] f32, out1: mel_len [B] f32.
//
// R9 lesson: limiter is makespan imbalance — 1MB zerofill blocks straggle
// (~30us each at per-CU share BW) behind a 39us store roofline. Fix:
//   kernel 1 (32 blocks): scan duration -> csum in d_ws + mel_out.
//   kernel 2 (4096 uniform fine blocks, NO scan prologue):
//     - expand: 1 phoneme/wave, reads 2 csum ints, row 2KB single-touch,
//       plain full-line 1KB stores (proven 6.9 TB/s path).
//     - zerofill: 64-frame (128KB) chunks, pure stores.

typedef float f32x4 __attribute__((ext_vector_type(4)));

constexpr int B   = 32;
constexpr int T   = 512;
constexpr int D   = 512;
constexpr int D4  = D / 4;        // 128 x 16B per row
constexpr int ML  = 4096;
constexpr int NTHREADS = 512;
constexpr int kZChunk = 64;                    // frames per zerofill block (128KB)
constexpr int kNumZ   = ML / kZChunk;          // 64 zerofill blocks / batch
constexpr int kNumE   = T / 8;                 // 64 expand blocks / batch (8 waves, 1 phoneme each)
constexpr int kBPB    = kNumE + kNumZ;         // 128 blocks per batch

__global__ __launch_bounds__(NTHREADS) void lr_scan(
    const int* __restrict__ duration,   // [B, T]
    int*       __restrict__ csum,       // [B, T] (d_ws)
    float*     __restrict__ mel_out)    // [B]
{
    const int b = blockIdx.x;
    const int t = threadIdx.x;
    const int lane = t & 63;
    const int wave = t >> 6;

    __shared__ int wsum[NTHREADS / 64];

    int v = duration[b * T + t];
    #pragma unroll
    for (int off = 1; off < 64; off <<= 1) {
        int n = __shfl_up(v, off, 64);
        if (lane >= off) v += n;
    }
    if (lane == 63) wsum[wave] = v;
    __syncthreads();
    int prev = 0;
    #pragma unroll
    for (int w = 0; w < NTHREADS / 64; ++w)
        if (w < wave) prev += wsum[w];
    v += prev;
    csum[b * T + t] = v;
    if (t == T - 1)
        mel_out[b] = (float)v;
}

__global__ __launch_bounds__(NTHREADS) void lr_main(
    const int*   __restrict__ csum,     // [B, T]
    const f32x4* __restrict__ x,        // [B, T, D4]
    f32x4*       __restrict__ out)      // [B, ML, D4]
{
    const int bid  = blockIdx.x;
    const int b    = bid / kBPB;
    const int r    = bid % kBPB;
    const int t    = threadIdx.x;
    const int lane = t & 63;
    const int wave = t >> 6;

    if (r < kNumE) {
        // ---- expand: this wave owns phoneme p ----
        const int p   = r * 8 + wave;
        const int e   = csum[b * T + p];
        const int s   = (p == 0) ? 0 : csum[b * T + p - 1];
        if (e > s) {
            const size_t xb = ((size_t)(b * T + p)) * D4;
            const f32x4 v0 = x[xb + lane];        // first 1KB of row
            const f32x4 v1 = x[xb + 64 + lane];   // second 1KB of row
            size_t o = ((size_t)(b * ML + s)) * D4;
            for (int j = s; j < e; ++j, o += D4) {
                out[o + lane]      = v0;          // full-line 1KB stores
                out[o + 64 + lane] = v1;
            }
        }
    } else {
        // ---- zerofill: frames [max(j0, mel), j0 + kZChunk) ----
        const int c   = r - kNumE;
        const int mel = csum[b * T + T - 1];
        const int j0  = c * kZChunk;
        const int lo  = (j0 > mel) ? j0 : mel;
        const int hi  = j0 + kZChunk;
        if (lo < hi) {
            const f32x4 zero = {0.f, 0.f, 0.f, 0.f};
            const size_t base = ((size_t)(b * ML + lo)) * D4;
            const int total = (hi - lo) * D4;
            for (int m = t; m < total; m += NTHREADS)
                out[base + m] = zero;
        }
    }
}

extern "C" void kernel_launch(void* const* d_in, const int* in_sizes, int n_in,
                              void* d_out, int out_size, void* d_ws, size_t ws_size,
                              hipStream_t stream) {
    const float* x   = (const float*)d_in[0];
    const int*   dur = (const int*)d_in[1];

    float* out     = (float*)d_out;                 // [B*ML*D] then [B]
    float* mel_out = out + (size_t)B * ML * D;
    int*   csum    = (int*)d_ws;                    // B*T ints = 64KB

    lr_scan<<<B, NTHREADS, 0, stream>>>(dur, csum, mel_out);
    lr_main<<<B * kBPB, NTHREADS, 0, stream>>>(csum, (const f32x4*)x, (f32x4*)out);
}